// Round 15
// baseline (151.996 us; speedup 1.0000x reference)
//
#include <hip/hip_runtime.h>

#define BATCH 4096
#define T 256
#define IN 64
#define CELL 128
#define ZDIM 256
#define OUTD 64
#define M 16   // batch rows per block (one MFMA row-tile)

using f32x4 = __attribute__((ext_vector_type(4))) float;
using f4    = __attribute__((ext_vector_type(4))) float;
using h16x8 = __attribute__((ext_vector_type(8))) _Float16;
using fp16x2 = __attribute__((ext_vector_type(2))) __fp16;   // cvt_pkrtz result type
typedef unsigned int u32t;

union h8cast { h16x8 v; fp16x2 h[4]; };
union pkcast { fp16x2 h; u32t u; };

#define MFMA16(A, B, C) __builtin_amdgcn_mfma_f32_16x16x32_f16(A, B, C, 0, 0, 0)

// gate for cell pair (colA=32w+2q, colB=colA+1) at row 4g+I.
// Weights/biases pre-scaled: f-cols by -log2e, g-cols by 2*log2e, so
// sigmoid(zf) = rcp(1+exp2(zf')) and tanh(zg) = 1-2*rcp(exp2(zg')+1).
#define GATEPK(I)                                                               \
  {                                                                             \
    float fgA = __builtin_amdgcn_rcpf(1.f + __builtin_amdgcn_exp2f(fa[I]));     \
    float thA = 1.f - 2.f * __builtin_amdgcn_rcpf(__builtin_amdgcn_exp2f(ga[I]) + 1.f); \
    float cnA = fgA * (cregA[I] - thA) + thA;                                   \
    float fgB = __builtin_amdgcn_rcpf(1.f + __builtin_amdgcn_exp2f(fb[I]));     \
    float thB = 1.f - 2.f * __builtin_amdgcn_rcpf(__builtin_amdgcn_exp2f(gb[I]) + 1.f); \
    float cnB = fgB * (cregB[I] - thB) + thB;                                   \
    cregA[I] = cnA; cregB[I] = cnB;                                             \
    pkcast pk_; pk_.h = __builtin_amdgcn_cvt_pkrtz(cnA, cnB);                   \
    *(u32t*)(cn_ + woPk[I]) = pk_.u;                                            \
  }

#define CVT8(D0, D1, S0, S1, S2, S3)                                            \
  {                                                                             \
    h8cast u0_, u1_;                                                            \
    u0_.h[0] = __builtin_amdgcn_cvt_pkrtz(S0[0], S0[1]);                        \
    u0_.h[1] = __builtin_amdgcn_cvt_pkrtz(S0[2], S0[3]);                        \
    u0_.h[2] = __builtin_amdgcn_cvt_pkrtz(S1[0], S1[1]);                        \
    u0_.h[3] = __builtin_amdgcn_cvt_pkrtz(S1[2], S1[3]);                        \
    u1_.h[0] = __builtin_amdgcn_cvt_pkrtz(S2[0], S2[1]);                        \
    u1_.h[1] = __builtin_amdgcn_cvt_pkrtz(S2[2], S2[3]);                        \
    u1_.h[2] = __builtin_amdgcn_cvt_pkrtz(S3[0], S3[1]);                        \
    u1_.h[3] = __builtin_amdgcn_cvt_pkrtz(S3[2], S3[3]);                        \
    D0 = u0_.v; D1 = u1_.v;                                                     \
  }

// One recurrence step at time TT (parity CUR), P = LDS read buffer.
// Phase order (each latency window has designated filler work):
//   1. ds_read c(TT) fragments              (latency filled by 2.)
//   2. CVT x(TT+2) -> xa_CUR; refill xr_CUR <- x(TT+4)
//   3. c-chains depth 4, seeded zx(TT)      (computed pre-barrier last step)
//   4. gates + packed ds_writes -> c(TT+1)
//   5. zx(TT+1) from xa_NXT: 8 pure-register MFMAs fill write-drain + skew
//   6. lgkmcnt(0) + s_barrier               (global prefetch stays in flight)
#define STEP(CUR, NXT, TT, P)                                                   \
  {                                                                             \
    const char* cb_ = cbuf[P];                                                  \
    h16x8 ca0 = *(const h16x8*)(cb_ + ro[0]);                                   \
    h16x8 ca1 = *(const h16x8*)(cb_ + ro[1]);                                   \
    h16x8 ca2 = *(const h16x8*)(cb_ + ro[2]);                                   \
    h16x8 ca3 = *(const h16x8*)(cb_ + ro[3]);                                   \
    /* fill ds_read latency: convert x(TT+2); refill raw regs with x(TT+4) */   \
    CVT8(xa_##CUR##0, xa_##CUR##1, xr_##CUR##0, xr_##CUR##1, xr_##CUR##2, xr_##CUR##3) \
    {                                                                           \
      const int tn = ((TT) + 4) & (T - 1);                                      \
      const float* xp = xbase + (size_t)tn * IN;                                \
      xr_##CUR##0 = *(const f4*)(xp);                                           \
      xr_##CUR##1 = *(const f4*)(xp + 4);                                       \
      xr_##CUR##2 = *(const f4*)(xp + 32);                                      \
      xr_##CUR##3 = *(const f4*)(xp + 36);                                      \
    }                                                                           \
    /* c-chains: 4 parallel, depth 4, seeded with zx(TT) */                     \
    f32x4 fa = MFMA16(ca0, bA2, zxf##CUR##A);                                   \
    f32x4 fb = MFMA16(ca0, bB2, zxf##CUR##B);                                   \
    f32x4 ga = MFMA16(ca0, bC2, zxg##CUR##A);                                   \
    f32x4 gb = MFMA16(ca0, bD2, zxg##CUR##B);                                   \
    fa = MFMA16(ca1, bA3, fa); fb = MFMA16(ca1, bB3, fb);                       \
    ga = MFMA16(ca1, bC3, ga); gb = MFMA16(ca1, bD3, gb);                       \
    fa = MFMA16(ca2, bA4, fa); fb = MFMA16(ca2, bB4, fb);                       \
    ga = MFMA16(ca2, bC4, ga); gb = MFMA16(ca2, bD4, gb);                       \
    fa = MFMA16(ca3, bA5, fa); fb = MFMA16(ca3, bB5, fb);                       \
    ga = MFMA16(ca3, bC5, ga); gb = MFMA16(ca3, bD5, gb);                       \
    /* gates -> c(TT+1) into cbuf[P^1] */                                       \
    char* cn_ = cbuf[(P) ^ 1];                                                  \
    GATEPK(0) GATEPK(1) GATEPK(2) GATEPK(3)                                     \
    /* zx(TT+1): pure-register MFMAs absorb ds_write drain + barrier skew */    \
    zxf##NXT##A = MFMA16(xa_##NXT##0, bA0, bqA);                                \
    zxf##NXT##B = MFMA16(xa_##NXT##0, bB0, bqB);                                \
    zxg##NXT##A = MFMA16(xa_##NXT##0, bC0, bqC);                                \
    zxg##NXT##B = MFMA16(xa_##NXT##0, bD0, bqD);                                \
    zxf##NXT##A = MFMA16(xa_##NXT##1, bA1, zxf##NXT##A);                        \
    zxf##NXT##B = MFMA16(xa_##NXT##1, bB1, zxf##NXT##B);                        \
    zxg##NXT##A = MFMA16(xa_##NXT##1, bC1, zxg##NXT##A);                        \
    zxg##NXT##B = MFMA16(xa_##NXT##1, bD1, zxg##NXT##B);                        \
    /* LDS-only barrier: ds_writes visible, global prefetch stays in flight */  \
    asm volatile("s_waitcnt lgkmcnt(0)\n\ts_barrier" ::: "memory");             \
  }

__global__ __launch_bounds__(256, 1)
void llrnn_f16(const float* __restrict__ in,   // [B,T,IN]
               const float* __restrict__ Km,   // [IN,ZDIM]
               const float* __restrict__ Rm,   // [CELL,ZDIM]
               const float* __restrict__ bz,   // [ZDIM]
               const float* __restrict__ Wd,   // [CELL,OUTD]
               const float* __restrict__ bd,   // [OUTD]
               float* __restrict__ out)        // [B,OUTD]
{
  // c state as fp16 [16 rows][128 cells], chunk-XOR-swizzled, double-buffered.
  // byte(r,j) = r*256 + 16*((j>>3)^(r&7)) + (2j&15)
  __shared__ __align__(16) char cbuf[2][M * CELL * 2];   // 2 x 4 KB
  __shared__ float cfin[M * CELL];

  const int tid = threadIdx.x;
  const int w = tid >> 6;        // wave 0..3
  const int l = tid & 63;
  const int q = l & 15;          // A-row / D-col within tile
  const int g = l >> 4;          // k-group 0..3
  const int rb = blockIdx.x * M;
  const int colA = 32 * w + 2 * q;    // even cell column owned by this lane
  const int colB = colA + 1;          // odd cell column

  // zero c(t=0) buffer (4 KB)
  {
    u32t* z0 = (u32t*)cbuf[0];
    z0[tid] = 0; z0[tid + 256] = 0; z0[tid + 512] = 0; z0[tid + 768] = 0;
  }

  const float SF = -1.44269504f;  // -log2(e): fold into f-gate weights
  const float SG =  2.88539008f;  //  2*log2(e): fold into g-gate weights

  // ---- preload scaled weight columns as fp16 frags ----
  h16x8 bA0,bA1,bA2,bA3,bA4,bA5, bB0,bB1,bB2,bB3,bB4,bB5,
        bC0,bC1,bC2,bC3,bC4,bC5, bD0,bD1,bD2,bD3,bD4,bD5;
#define LOADW(DST, COL, KT, SC)                                                 \
  {                                                                             \
    _Pragma("unroll") for (int e = 0; e < 8; ++e) {                             \
      const int krow = 32 * (KT) + 8 * g + e;                                   \
      const float* src = ((KT) < 2) ? (Km + (size_t)krow * ZDIM)                \
                                    : (Rm + (size_t)(krow - IN) * ZDIM);        \
      DST[e] = (_Float16)(src[COL] * (SC));                                     \
    }                                                                           \
  }
  LOADW(bA0,colA,0,SF) LOADW(bA1,colA,1,SF) LOADW(bA2,colA,2,SF)
  LOADW(bA3,colA,3,SF) LOADW(bA4,colA,4,SF) LOADW(bA5,colA,5,SF)
  LOADW(bB0,colB,0,SF) LOADW(bB1,colB,1,SF) LOADW(bB2,colB,2,SF)
  LOADW(bB3,colB,3,SF) LOADW(bB4,colB,4,SF) LOADW(bB5,colB,5,SF)
  LOADW(bC0,colA+CELL,0,SG) LOADW(bC1,colA+CELL,1,SG) LOADW(bC2,colA+CELL,2,SG)
  LOADW(bC3,colA+CELL,3,SG) LOADW(bC4,colA+CELL,4,SG) LOADW(bC5,colA+CELL,5,SG)
  LOADW(bD0,colB+CELL,0,SG) LOADW(bD1,colB+CELL,1,SG) LOADW(bD2,colB+CELL,2,SG)
  LOADW(bD3,colB+CELL,3,SG) LOADW(bD4,colB+CELL,4,SG) LOADW(bD5,colB+CELL,5,SG)
#undef LOADW
  // pin weight frags in AGPRs: MFMA reads A/B operands from AGPR natively
  // (zero copies), freeing ~96 arch VGPRs for the copy-sensitive working set
  // (xr loads, fa/ga gate inputs, temps). Single-variable change vs R14.
  asm volatile("" : "+a"(bA0),"+a"(bA1),"+a"(bA2),"+a"(bA3),"+a"(bA4),"+a"(bA5),
                    "+a"(bB0),"+a"(bB1),"+a"(bB2),"+a"(bB3),"+a"(bB4),"+a"(bB5),
                    "+a"(bC0),"+a"(bC1),"+a"(bC2),"+a"(bC3),"+a"(bC4),"+a"(bC5),
                    "+a"(bD0),"+a"(bD1),"+a"(bD2),"+a"(bD3),"+a"(bD4),"+a"(bD5));

  const float bA_ = bz[colA] * SF, bB_ = bz[colB] * SF;
  const float bC_ = bz[colA + CELL] * SG, bD_ = bz[colB + CELL] * SG;
  f32x4 bqA = {bA_, bA_, bA_, bA_};
  f32x4 bqB = {bB_, bB_, bB_, bB_};
  f32x4 bqC = {bC_, bC_, bC_, bC_};
  f32x4 bqD = {bD_, bD_, bD_, bD_};
  asm volatile("" : "+v"(bqA), "+v"(bqB), "+v"(bqC), "+v"(bqD));

  // LDS byte offsets
  int ro[4];   // read: row q, cells 32ct+8g..+8
#pragma unroll
  for (int ct = 0; ct < 4; ++ct)
    ro[ct] = q * 256 + 16 * ((4 * ct + g) ^ (q & 7));
  int woPk[4]; // packed write: row 4g+i, cells colA,colB (one u32)
#pragma unroll
  for (int i = 0; i < 4; ++i) {
    const int r = 4 * g + i;
    woPk[i] = r * 256 + 16 * ((4 * w + (q >> 2)) ^ (r & 7)) + ((4 * q) & 15);
  }

  // per-lane x base (row rb+q, k-offset 8g); step offset is uniform
  const float* xbase = in + (size_t)(rb + q) * T * IN + 8 * g;

  // ---- prologue: x(0),x(1) converted; zx(0) computed; xr <- x(2),x(3) ----
  f4 xr_E0 = *(const f4*)(xbase);
  f4 xr_E1 = *(const f4*)(xbase + 4);
  f4 xr_E2 = *(const f4*)(xbase + 32);
  f4 xr_E3 = *(const f4*)(xbase + 36);
  f4 xr_O0 = *(const f4*)(xbase + IN);
  f4 xr_O1 = *(const f4*)(xbase + IN + 4);
  f4 xr_O2 = *(const f4*)(xbase + IN + 32);
  f4 xr_O3 = *(const f4*)(xbase + IN + 36);

  h16x8 xa_E0, xa_E1, xa_O0, xa_O1;
  CVT8(xa_E0, xa_E1, xr_E0, xr_E1, xr_E2, xr_E3)   // x(0)
  CVT8(xa_O0, xa_O1, xr_O0, xr_O1, xr_O2, xr_O3)   // x(1)

  f32x4 zxfEA, zxfEB, zxgEA, zxgEB, zxfOA, zxfOB, zxgOA, zxgOB;
  // zx(0) = bias + x(0)@K
  zxfEA = MFMA16(xa_E0, bA0, bqA);
  zxfEB = MFMA16(xa_E0, bB0, bqB);
  zxgEA = MFMA16(xa_E0, bC0, bqC);
  zxgEB = MFMA16(xa_E0, bD0, bqD);
  zxfEA = MFMA16(xa_E1, bA1, zxfEA);
  zxfEB = MFMA16(xa_E1, bB1, zxfEB);
  zxgEA = MFMA16(xa_E1, bC1, zxgEA);
  zxgEB = MFMA16(xa_E1, bD1, zxgEB);

  // refill raw regs: xr_E <- x(2), xr_O <- x(3)
  xr_E0 = *(const f4*)(xbase + 2 * IN);
  xr_E1 = *(const f4*)(xbase + 2 * IN + 4);
  xr_E2 = *(const f4*)(xbase + 2 * IN + 32);
  xr_E3 = *(const f4*)(xbase + 2 * IN + 36);
  xr_O0 = *(const f4*)(xbase + 3 * IN);
  xr_O1 = *(const f4*)(xbase + 3 * IN + 4);
  xr_O2 = *(const f4*)(xbase + 3 * IN + 32);
  xr_O3 = *(const f4*)(xbase + 3 * IN + 36);

  f32x4 cregA = {0.f, 0.f, 0.f, 0.f};   // fp32 master state, col colA
  f32x4 cregB = {0.f, 0.f, 0.f, 0.f};   // fp32 master state, col colB

  __syncthreads();   // c(t=0) zeros visible

  for (int t = 0; t < T; t += 2) {
    STEP(E, O, t, 0)       // even: consumes zxE, produces zxO; cbuf[0]->[1]
    STEP(O, E, t + 1, 1)   // odd:  consumes zxO, produces zxE; cbuf[1]->[0]
  }

  // ---- final c (fp32) to LDS, dense epilogue out = h @ Wd + bd ----
#pragma unroll
  for (int i = 0; i < 4; ++i) {
    cfin[(4 * g + i) * CELL + colA] = cregA[i];
    cfin[(4 * g + i) * CELL + colB] = cregB[i];
  }
  __syncthreads();

  const int o = tid & 63;
  const int rp = tid >> 6;   // 0..3: rows rp, rp+4, rp+8, rp+12
  float a0 = bd[o], a1 = bd[o], a2 = bd[o], a3 = bd[o];
#pragma unroll 4
  for (int k = 0; k < CELL; ++k) {
    const float wv = Wd[(size_t)k * OUTD + o];
    a0 += cfin[rp * CELL + k] * wv;
    a1 += cfin[(rp + 4) * CELL + k] * wv;
    a2 += cfin[(rp + 8) * CELL + k] * wv;
    a3 += cfin[(rp + 12) * CELL + k] * wv;
  }
  out[(size_t)(rb + rp) * OUTD + o] = a0;
  out[(size_t)(rb + rp + 4) * OUTD + o] = a1;
  out[(size_t)(rb + rp + 8) * OUTD + o] = a2;
  out[(size_t)(rb + rp + 12) * OUTD + o] = a3;
}

extern "C" void kernel_launch(void* const* d_in, const int* in_sizes, int n_in,
                              void* d_out, int out_size, void* d_ws, size_t ws_size,
                              hipStream_t stream) {
  const float* in  = (const float*)d_in[0];
  const float* Km  = (const float*)d_in[1];
  const float* Rm  = (const float*)d_in[2];
  const float* bz  = (const float*)d_in[3];
  const float* Wd  = (const float*)d_in[4];
  const float* bd  = (const float*)d_in[5];
  float* out = (float*)d_out;

  dim3 grid(BATCH / M);   // 256 blocks -> 1 per CU
  dim3 block(256);        // 4 waves -> 1 per SIMD
  hipLaunchKernelGGL(llrnn_f16, grid, block, 0, stream,
                     in, Km, Rm, bz, Wd, bd, out);
}

// Round 16
// 149.811 us; speedup vs baseline: 1.0146x; 1.0146x over previous
//
#include <hip/hip_runtime.h>

#define BATCH 4096
#define T 256
#define IN 64
#define CELL 128
#define ZDIM 256
#define OUTD 64
#define M 16   // batch rows per block (one MFMA row-tile)

using f32x4 = __attribute__((ext_vector_type(4))) float;
using f4    = __attribute__((ext_vector_type(4))) float;
using h16x8 = __attribute__((ext_vector_type(8))) _Float16;
using fp16x2 = __attribute__((ext_vector_type(2))) __fp16;
typedef unsigned int u32t;

union h8cast { h16x8 v; fp16x2 h[4]; };
union pkcast { fp16x2 h; u32t u; };

#define MFMA16(A, B, C) __builtin_amdgcn_mfma_f32_16x16x32_f16(A, B, C, 0, 0, 0)

#define LDSBAR asm volatile("s_waitcnt lgkmcnt(0)\n\ts_barrier" ::: "memory")

// gate for cell pair (colA, colB) at row 4g+I (consumer).
// Weights/biases pre-scaled: f-cols by -log2e, g-cols by 2*log2e, so
// sigmoid(zf) = rcp(1+exp2(zf')) and tanh(zg) = 1-2*rcp(exp2(zg')+1).
#define GATEPK(I)                                                               \
  {                                                                             \
    float fgA = __builtin_amdgcn_rcpf(1.f + __builtin_amdgcn_exp2f(fa[I]));     \
    float thA = 1.f - 2.f * __builtin_amdgcn_rcpf(__builtin_amdgcn_exp2f(ga[I]) + 1.f); \
    float cnA = fgA * (cregA[I] - thA) + thA;                                   \
    float fgB = __builtin_amdgcn_rcpf(1.f + __builtin_amdgcn_exp2f(fb[I]));     \
    float thB = 1.f - 2.f * __builtin_amdgcn_rcpf(__builtin_amdgcn_exp2f(gb[I]) + 1.f); \
    float cnB = fgB * (cregB[I] - thB) + thB;                                   \
    cregA[I] = cnA; cregB[I] = cnB;                                             \
    pkcast pk_; pk_.h = __builtin_amdgcn_cvt_pkrtz(cnA, cnB);                   \
    *(u32t*)(cn_ + woPk[I]) = pk_.u;                                            \
  }

#define CVT8(D0, D1, S0, S1, S2, S3)                                            \
  {                                                                             \
    h8cast u0_, u1_;                                                            \
    u0_.h[0] = __builtin_amdgcn_cvt_pkrtz(S0[0], S0[1]);                        \
    u0_.h[1] = __builtin_amdgcn_cvt_pkrtz(S0[2], S0[3]);                        \
    u0_.h[2] = __builtin_amdgcn_cvt_pkrtz(S1[0], S1[1]);                        \
    u0_.h[3] = __builtin_amdgcn_cvt_pkrtz(S1[2], S1[3]);                        \
    u1_.h[0] = __builtin_amdgcn_cvt_pkrtz(S2[0], S2[1]);                        \
    u1_.h[1] = __builtin_amdgcn_cvt_pkrtz(S2[2], S2[3]);                        \
    u1_.h[2] = __builtin_amdgcn_cvt_pkrtz(S3[0], S3[1]);                        \
    u1_.h[3] = __builtin_amdgcn_cvt_pkrtz(S3[2], S3[3]);                        \
    D0 = u0_.v; D1 = u1_.v;                                                     \
  }

// ---- consumer step: recurrence only. Reads c(TT) from cbuf[P] and zx(TT)
// seed quads from zxb buf P; writes c(TT+1) to cbuf[P^1]. 16 MFMAs.
#define CSTEP(P)                                                                \
  {                                                                             \
    const char* cb_ = cbuf[P];                                                  \
    h16x8 ca0 = *(const h16x8*)(cb_ + ro[0]);                                   \
    h16x8 ca1 = *(const h16x8*)(cb_ + ro[1]);                                   \
    h16x8 ca2 = *(const h16x8*)(cb_ + ro[2]);                                   \
    h16x8 ca3 = *(const h16x8*)(cb_ + ro[3]);                                   \
    const char* zb_ = zxb + (P) * 16384 + zoff;                                 \
    f32x4 sfA = *(const f32x4*)(zb_);                                           \
    f32x4 sfB = *(const f32x4*)(zb_ + 1024);                                    \
    f32x4 sgA = *(const f32x4*)(zb_ + 2048);                                    \
    f32x4 sgB = *(const f32x4*)(zb_ + 3072);                                    \
    f32x4 fa = MFMA16(ca0, bA2, sfA);                                           \
    f32x4 fb = MFMA16(ca0, bB2, sfB);                                           \
    f32x4 ga = MFMA16(ca0, bC2, sgA);                                           \
    f32x4 gb = MFMA16(ca0, bD2, sgB);                                           \
    fa = MFMA16(ca1, bA3, fa); fb = MFMA16(ca1, bB3, fb);                       \
    ga = MFMA16(ca1, bC3, ga); gb = MFMA16(ca1, bD3, gb);                       \
    fa = MFMA16(ca2, bA4, fa); fb = MFMA16(ca2, bB4, fb);                       \
    ga = MFMA16(ca2, bC4, ga); gb = MFMA16(ca2, bD4, gb);                       \
    fa = MFMA16(ca3, bA5, fa); fb = MFMA16(ca3, bB5, fb);                       \
    ga = MFMA16(ca3, bC5, ga); gb = MFMA16(ca3, bD5, gb);                       \
    char* cn_ = cbuf[(P) ^ 1];                                                  \
    GATEPK(0) GATEPK(1) GATEPK(2) GATEPK(3)                                     \
    LDSBAR;                                                                     \
  }

// ---- producer step at time TT: xa holds f16(x(TT+1)); emit zx(TT+1) to
// zxb buf PN=(TT+1)&1; then convert x(TT+2) from XP*, refill XP* <- x(TT+4).
#define PSTEP(XP0, XP1, XP2, XP3, TT, PN)                                       \
  {                                                                             \
    f32x4 zfA = MFMA16(xa0, kA0, bqA);                                          \
    f32x4 zfB = MFMA16(xa0, kB0, bqB);                                          \
    f32x4 zgA = MFMA16(xa0, kC0, bqC);                                          \
    f32x4 zgB = MFMA16(xa0, kD0, bqD);                                          \
    zfA = MFMA16(xa1, kA1, zfA);                                                \
    zfB = MFMA16(xa1, kB1, zfB);                                                \
    zgA = MFMA16(xa1, kC1, zgA);                                                \
    zgB = MFMA16(xa1, kD1, zgB);                                                \
    char* zw_ = zxb + (PN) * 16384 + zoff;                                      \
    *(f32x4*)(zw_)        = zfA;                                                \
    *(f32x4*)(zw_ + 1024) = zfB;                                                \
    *(f32x4*)(zw_ + 2048) = zgA;                                                \
    *(f32x4*)(zw_ + 3072) = zgB;                                                \
    CVT8(xa0, xa1, XP0, XP1, XP2, XP3)                                          \
    {                                                                           \
      const int tn = ((TT) + 4) & (T - 1);                                      \
      const float* xp = xbase + (size_t)tn * IN;                                \
      XP0 = *(const f4*)(xp);                                                   \
      XP1 = *(const f4*)(xp + 4);                                               \
      XP2 = *(const f4*)(xp + 32);                                              \
      XP3 = *(const f4*)(xp + 36);                                              \
    }                                                                           \
    LDSBAR;                                                                     \
  }

__global__ __launch_bounds__(512, 1)
void llrnn_pc(const float* __restrict__ in,   // [B,T,IN]
              const float* __restrict__ Km,   // [IN,ZDIM]
              const float* __restrict__ Rm,   // [CELL,ZDIM]
              const float* __restrict__ bz,   // [ZDIM]
              const float* __restrict__ Wd,   // [CELL,OUTD]
              const float* __restrict__ bd,   // [OUTD]
              float* __restrict__ out)        // [B,OUTD]
{
  // c state fp16, chunk-XOR-swizzled, double-buffered (8 KB);
  // zx staging: [2 buf][4 regions][4 quads][64 lanes][16 B] = 32 KB,
  // lane-contiguous -> conflict-free b128 on both sides.
  __shared__ __align__(16) char cbuf[2][M * CELL * 2];
  __shared__ __align__(16) char zxb[2 * 16384];
  __shared__ float cfin[M * CELL];

  const int tid = threadIdx.x;
  const int w = tid >> 6;        // 0..3 consumer, 4..7 producer
  const int l = tid & 63;
  const int q = l & 15;
  const int g = l >> 4;
  const int rb = blockIdx.x * M;

  const float SF = -1.44269504f;
  const float SG =  2.88539008f;

  // zero c(t=0) buffer (4 KB, 512 threads x 2 u32)
  {
    u32t* z0 = (u32t*)cbuf[0];
    z0[tid] = 0; z0[tid + 512] = 0;
  }
  __syncthreads();

  if (w < 4) {
    // ================= CONSUMER (waves 0-3): the recurrence =================
    const int colA = 32 * w + 2 * q;
    const int colB = colA + 1;
    const int zoff = w * 4096 + l * 16;   // region w, quad stride 1024

    // R-weight frags (k-tiles 0..3 of R, scaled), pinned in VGPRs
    h16x8 bA2,bA3,bA4,bA5, bB2,bB3,bB4,bB5, bC2,bC3,bC4,bC5, bD2,bD3,bD4,bD5;
#define LOADR(DST, COL, RT, SC)                                                 \
    {                                                                           \
      _Pragma("unroll") for (int e = 0; e < 8; ++e) {                           \
        const int krow = 32 * (RT) + 8 * g + e;                                 \
        DST[e] = (_Float16)(Rm[(size_t)krow * ZDIM + (COL)] * (SC));            \
      }                                                                         \
    }
    LOADR(bA2,colA,0,SF) LOADR(bA3,colA,1,SF) LOADR(bA4,colA,2,SF) LOADR(bA5,colA,3,SF)
    LOADR(bB2,colB,0,SF) LOADR(bB3,colB,1,SF) LOADR(bB4,colB,2,SF) LOADR(bB5,colB,3,SF)
    LOADR(bC2,colA+CELL,0,SG) LOADR(bC3,colA+CELL,1,SG) LOADR(bC4,colA+CELL,2,SG) LOADR(bC5,colA+CELL,3,SG)
    LOADR(bD2,colB+CELL,0,SG) LOADR(bD3,colB+CELL,1,SG) LOADR(bD4,colB+CELL,2,SG) LOADR(bD5,colB+CELL,3,SG)
#undef LOADR
    asm volatile("" : "+v"(bA2),"+v"(bA3),"+v"(bA4),"+v"(bA5),
                      "+v"(bB2),"+v"(bB3),"+v"(bB4),"+v"(bB5),
                      "+v"(bC2),"+v"(bC3),"+v"(bC4),"+v"(bC5),
                      "+v"(bD2),"+v"(bD3),"+v"(bD4),"+v"(bD5));

    int ro[4];
#pragma unroll
    for (int ct = 0; ct < 4; ++ct)
      ro[ct] = q * 256 + 16 * ((4 * ct + g) ^ (q & 7));
    int woPk[4];
#pragma unroll
    for (int i = 0; i < 4; ++i) {
      const int r = 4 * g + i;
      woPk[i] = r * 256 + 16 * ((4 * w + (q >> 2)) ^ (r & 7)) + ((4 * q) & 15);
    }

    f32x4 cregA = {0.f, 0.f, 0.f, 0.f};
    f32x4 cregB = {0.f, 0.f, 0.f, 0.f};

    LDSBAR;   // matches producer's zx(0)-publish barrier

    for (int t = 0; t < T; t += 2) {
      CSTEP(0)
      CSTEP(1)
    }

    // final c -> cfin, dense epilogue
#pragma unroll
    for (int i = 0; i < 4; ++i) {
      cfin[(4 * g + i) * CELL + colA] = cregA[i];
      cfin[(4 * g + i) * CELL + colB] = cregB[i];
    }
    LDSBAR;   // matches producer's post-loop barrier

    const int o = tid & 63;
    const int rp = tid >> 6;   // 0..3
    float a0 = bd[o], a1 = bd[o], a2 = bd[o], a3 = bd[o];
#pragma unroll 4
    for (int k = 0; k < CELL; ++k) {
      const float wv = Wd[(size_t)k * OUTD + o];
      a0 += cfin[rp * CELL + k] * wv;
      a1 += cfin[(rp + 4) * CELL + k] * wv;
      a2 += cfin[(rp + 8) * CELL + k] * wv;
      a3 += cfin[(rp + 12) * CELL + k] * wv;
    }
    out[(size_t)(rb + rp) * OUTD + o] = a0;
    out[(size_t)(rb + rp + 4) * OUTD + o] = a1;
    out[(size_t)(rb + rp + 8) * OUTD + o] = a2;
    out[(size_t)(rb + rp + 12) * OUTD + o] = a3;
  } else {
    // ================= PRODUCER (waves 4-7): zx = bias + x@K =================
    const int pw = w - 4;
    const int colA = 32 * pw + 2 * q;
    const int colB = colA + 1;
    const int zoff = pw * 4096 + l * 16;

    // K-weight frags (k-tiles 0..1 of K, scaled), pinned
    h16x8 kA0,kA1, kB0,kB1, kC0,kC1, kD0,kD1;
#define LOADK(DST, COL, KT, SC)                                                 \
    {                                                                           \
      _Pragma("unroll") for (int e = 0; e < 8; ++e) {                           \
        const int krow = 32 * (KT) + 8 * g + e;                                 \
        DST[e] = (_Float16)(Km[(size_t)krow * ZDIM + (COL)] * (SC));            \
      }                                                                         \
    }
    LOADK(kA0,colA,0,SF) LOADK(kA1,colA,1,SF)
    LOADK(kB0,colB,0,SF) LOADK(kB1,colB,1,SF)
    LOADK(kC0,colA+CELL,0,SG) LOADK(kC1,colA+CELL,1,SG)
    LOADK(kD0,colB+CELL,0,SG) LOADK(kD1,colB+CELL,1,SG)
#undef LOADK
    asm volatile("" : "+v"(kA0),"+v"(kA1),"+v"(kB0),"+v"(kB1),
                      "+v"(kC0),"+v"(kC1),"+v"(kD0),"+v"(kD1));

    const float bA_ = bz[colA] * SF, bB_ = bz[colB] * SF;
    const float bC_ = bz[colA + CELL] * SG, bD_ = bz[colB + CELL] * SG;
    f32x4 bqA = {bA_, bA_, bA_, bA_};
    f32x4 bqB = {bB_, bB_, bB_, bB_};
    f32x4 bqC = {bC_, bC_, bC_, bC_};
    f32x4 bqD = {bD_, bD_, bD_, bD_};

    const float* xbase = in + (size_t)(rb + q) * T * IN + 8 * g;

    // prologue: zx(0) -> buf0; xa = f16(x(1)); xr_E=x(2), xr_O=x(3)
    f4 a0_ = *(const f4*)(xbase);
    f4 a1_ = *(const f4*)(xbase + 4);
    f4 a2_ = *(const f4*)(xbase + 32);
    f4 a3_ = *(const f4*)(xbase + 36);
    h16x8 xa0, xa1;
    CVT8(xa0, xa1, a0_, a1_, a2_, a3_)    // x(0)
    {
      f32x4 zfA = MFMA16(xa0, kA0, bqA);
      f32x4 zfB = MFMA16(xa0, kB0, bqB);
      f32x4 zgA = MFMA16(xa0, kC0, bqC);
      f32x4 zgB = MFMA16(xa0, kD0, bqD);
      zfA = MFMA16(xa1, kA1, zfA);
      zfB = MFMA16(xa1, kB1, zfB);
      zgA = MFMA16(xa1, kC1, zgA);
      zgB = MFMA16(xa1, kD1, zgB);
      char* zw_ = zxb + zoff;             // buf 0
      *(f32x4*)(zw_)        = zfA;
      *(f32x4*)(zw_ + 1024) = zfB;
      *(f32x4*)(zw_ + 2048) = zgA;
      *(f32x4*)(zw_ + 3072) = zgB;
    }
    f4 xe0 = *(const f4*)(xbase + 2 * IN);
    f4 xe1 = *(const f4*)(xbase + 2 * IN + 4);
    f4 xe2 = *(const f4*)(xbase + 2 * IN + 32);
    f4 xe3 = *(const f4*)(xbase + 2 * IN + 36);
    f4 xo0 = *(const f4*)(xbase + 3 * IN);
    f4 xo1 = *(const f4*)(xbase + 3 * IN + 4);
    f4 xo2 = *(const f4*)(xbase + 3 * IN + 32);
    f4 xo3 = *(const f4*)(xbase + 3 * IN + 36);
    a0_ = *(const f4*)(xbase + IN);
    a1_ = *(const f4*)(xbase + IN + 4);
    a2_ = *(const f4*)(xbase + IN + 32);
    a3_ = *(const f4*)(xbase + IN + 36);
    CVT8(xa0, xa1, a0_, a1_, a2_, a3_)    // x(1)

    LDSBAR;   // publish zx(0); matches consumer pre-loop barrier

    for (int t = 0; t < T; t += 2) {
      PSTEP(xe0, xe1, xe2, xe3, t, 1)       // zx(t+1) -> buf1
      PSTEP(xo0, xo1, xo2, xo3, t + 1, 0)   // zx(t+2) -> buf0
    }

    LDSBAR;   // matches consumer post-loop barrier; then exit
  }
}

extern "C" void kernel_launch(void* const* d_in, const int* in_sizes, int n_in,
                              void* d_out, int out_size, void* d_ws, size_t ws_size,
                              hipStream_t stream) {
  const float* in  = (const float*)d_in[0];
  const float* Km  = (const float*)d_in[1];
  const float* Rm  = (const float*)d_in[2];
  const float* bz  = (const float*)d_in[3];
  const float* Wd  = (const float*)d_in[4];
  const float* bd  = (const float*)d_in[5];
  float* out = (float*)d_out;

  dim3 grid(BATCH / M);   // 256 blocks -> 1 per CU
  dim3 block(512);        // 8 waves: 4 consumer + 4 producer (1+1 per SIMD)
  hipLaunchKernelGGL(llrnn_pc, grid, block, 0, stream,
                     in, Km, Rm, bz, Wd, bd, out);
}